// Round 4
// baseline (735.272 us; speedup 1.0000x reference)
//
#include <hip/hip_runtime.h>

#define BATCH 128
#define GRID  256
#define BLOCK 512
#define NWAVE 8

__device__ __constant__ float GC[16][4] = {
  {0,0,0,0},{0,0,0,1},{0,1,0,-1},{0,1,0,0},
  {0,0,1,-1},{0,0,1,0},{0,1,1,-2},{0,1,1,-1},
  {1,-1,-1,1},{1,-1,-1,2},{1,0,-1,0},{1,0,-1,1},
  {1,-1,0,0},{1,-1,0,1},{1,0,0,-1},{1,0,0,0}};

// ---- ws layout (float offsets); bar state in first 64 floats ----
#define WS_BAR   0
#define WS_MC1   64
#define WS_MC2   (WS_MC1 + 896)
#define WS_MC3   (WS_MC2 + 3584)
#define WS_MC4   (WS_MC3 + 14336)
#define WS_ML1   (WS_MC4 + 28672)
#define WS_ML2   (WS_ML1 + 163840)
#define WS_ML3   (WS_ML2 + 81920)
#define WS_XT    (WS_ML3 + 40960)
#define WS_H1    (WS_XT  + 393216)
#define WS_H2    (WS_H1  + 1048576)
#define WS_H3    (WS_H2  + 1048576)
#define WS_H4    (WS_H3  + 1048576)
#define WS_G1    (WS_H4  + 524288)
#define WS_G2    (WS_G1  + 5242880)
#define WS_G3    (WS_G2  + 2621440)

struct Params {
  const float* x;
  const int*   c1i; const float* c1w;
  const int*   c2i; const float* c2w;
  const int*   c3i; const float* c3w;
  const int*   c4i; const float* c4w;
  const int*   l1a; const int* l1b; const float* l1w;
  const int*   l2a; const int* l2b; const float* l2w;
  const int*   l3a; const int* l3b; const float* l3w;
  float* ws;
  float* out;
};

__global__ void bar_init(unsigned* bar) {
  if (threadIdx.x < 32) bar[threadIdx.x] = 0u;
}

__device__ __forceinline__ void grid_barrier(unsigned* bar, int phase) {
  __syncthreads();
  if (threadIdx.x == 0) {
    __threadfence();
    unsigned* cnt = bar + phase * 2;
    unsigned* flg = bar + phase * 2 + 1;
    unsigned old = __hip_atomic_fetch_add(cnt, 1u, __ATOMIC_ACQ_REL,
                                          __HIP_MEMORY_SCOPE_AGENT);
    if (old == GRID - 1) {
      __hip_atomic_store(flg, 1u, __ATOMIC_RELEASE, __HIP_MEMORY_SCOPE_AGENT);
    } else {
      while (__hip_atomic_load(flg, __ATOMIC_ACQUIRE,
                               __HIP_MEMORY_SCOPE_AGENT) == 0u) {
        __builtin_amdgcn_s_sleep(1);
      }
    }
  }
  __syncthreads();
  __threadfence();  // agent-scope acquire: invalidate L1 for all threads
}

__device__ __forceinline__ float2 gate2(float2 a, float2 b, float4 w) {
  float2 r;
  r.x = fmaf(w.w, a.x * b.x, fmaf(w.z, b.x, fmaf(w.y, a.x, w.x)));
  r.y = fmaf(w.w, a.y * b.y, fmaf(w.z, b.y, fmaf(w.y, a.y, w.x)));
  return r;
}

// ---- phase 0 helpers ----
__device__ void mix_one(const float* lp, float* op) {
  float e[16];
  float s = 0.f;
  #pragma unroll
  for (int i = 0; i < 16; ++i) { e[i] = __expf(lp[i]); s += e[i]; }
  float inv = 1.0f / s;
  float w0 = 0.f, w1 = 0.f, w2 = 0.f, w3 = 0.f;
  #pragma unroll
  for (int i = 0; i < 16; ++i) {
    float p = e[i] * inv;
    w0 = fmaf(p, GC[i][0], w0);
    w1 = fmaf(p, GC[i][1], w1);
    w2 = fmaf(p, GC[i][2], w2);
    w3 = fmaf(p, GC[i][3], w3);
  }
  op[0] = w0; op[1] = w1; op[2] = w2; op[3] = w3;
}

// ---- conv phase: transposed (C*H*W, B) -> (O*PH*PW, B) ----
template <int C, int H, int W, int O, bool BIN, int RPW>
__device__ void conv_phase(const float* in_t, const int* li_g,
                           const float* m, float* out_t) {
  constexpr int PH = H / 2, PWD = W / 2, PIX = PH * PWD;
  int wave = threadIdx.x >> 6;
  int b2   = threadIdx.x & 63;
  int q0 = blockIdx.x * (NWAVE * RPW) + wave * RPW;
  for (int r = 0; r < RPW; ++r) {
    int q = __builtin_amdgcn_readfirstlane(q0 + r);
    int o = q / PIX;
    int p = q - o * PIX;
    int ph = p / PWD;
    int pw = p - ph * PWD;

    const int* li = li_g + o * 8;
    const float4* mwv = (const float4*)(m + o * 28);
    float4 w0 = mwv[0], w1 = mwv[1], w2 = mwv[2], w3 = mwv[3];
    float4 w4 = mwv[4], w5 = mwv[5], w6 = mwv[6];

    float2 best = {-1e30f, -1e30f};
    #pragma unroll
    for (int half = 0; half < 2; ++half) {
      float2 v[2][8];
      #pragma unroll
      for (int l = 0; l < 8; ++l) {
        int idx = li[l];
        int c = idx / 9;
        int k = idx - c * 9;
        int di = k / 3 - 1;
        int dj = (k - (k / 3) * 3) - 1;
        int srcc = c;
        float th = 0.f;
        if (BIN) {
          int ti = c / 3;
          srcc = c - ti * 3;
          th = 0.25f * (float)(ti + 1);
        }
        const float2* base =
            (const float2*)(in_t + (size_t)(srcc * H * W) * BATCH) + b2;
        int y = 2 * ph + half + di;
        #pragma unroll
        for (int pi = 0; pi < 2; ++pi) {
          int x = 2 * pw + pi + dj;
          float2 val = {0.f, 0.f};
          if ((unsigned)y < (unsigned)H && (unsigned)x < (unsigned)W) {
            val = base[(size_t)(y * W + x) * 64];
            if (BIN) {
              val.x = (val.x > th) ? 1.f : 0.f;
              val.y = (val.y > th) ? 1.f : 0.f;
            }
          }
          v[pi][l] = val;
        }
      }
      #pragma unroll
      for (int pi = 0; pi < 2; ++pi) {
        float2 u0 = gate2(v[pi][0], v[pi][1], w0);
        float2 u1 = gate2(v[pi][2], v[pi][3], w1);
        float2 u2 = gate2(v[pi][4], v[pi][5], w2);
        float2 u3 = gate2(v[pi][6], v[pi][7], w3);
        float2 s0 = gate2(u0, u1, w4);
        float2 s1 = gate2(u2, u3, w5);
        float2 rr = gate2(s0, s1, w6);
        best.x = fmaxf(best.x, rr.x);
        best.y = fmaxf(best.y, rr.y);
      }
    }
    ((float2*)(out_t + (size_t)q * BATCH))[b2] = best;
  }
}

template <int RPW>
__device__ void logic_phase(const float* in, const int* aidx, const int* bidx,
                            const float* m, float* out) {
  int wave = threadIdx.x >> 6;
  int b2   = threadIdx.x & 63;
  int q0 = blockIdx.x * (NWAVE * RPW) + wave * RPW;
  #pragma unroll 4
  for (int it = 0; it < RPW; ++it) {
    int j = __builtin_amdgcn_readfirstlane(q0 + it);
    int ai = aidx[j];
    int bi = bidx[j];
    float4 w = ((const float4*)m)[j];
    float2 a  = ((const float2*)(in + (size_t)ai * BATCH))[b2];
    float2 bb = ((const float2*)(in + (size_t)bi * BATCH))[b2];
    ((float2*)(out + (size_t)j * BATCH))[b2] = gate2(a, bb, w);
  }
}

__device__ void gsum_phase(const float* g3, float* out) {
  int wave = threadIdx.x >> 6;
  int b2   = threadIdx.x & 63;
  int q0 = blockIdx.x * 40 + wave * 5;
  float2 s = {0.f, 0.f};
  int cls = q0 >> 10;
  for (int it = 0; it < 5; ++it) {
    int q = q0 + it;
    int c = q >> 10;
    if (c != cls) {
      atomicAdd(&out[(2 * b2) * 10 + cls], s.x * 0.01f);
      atomicAdd(&out[(2 * b2 + 1) * 10 + cls], s.y * 0.01f);
      s.x = 0.f; s.y = 0.f;
      cls = c;
    }
    float2 v = ((const float2*)(g3 + (size_t)q * BATCH))[b2];
    s.x += v.x; s.y += v.y;
  }
  atomicAdd(&out[(2 * b2) * 10 + cls], s.x * 0.01f);
  atomicAdd(&out[(2 * b2 + 1) * 10 + cls], s.y * 0.01f);
}

__global__ __launch_bounds__(BLOCK, 2) void fused_net(Params P) {
  float* ws = P.ws;
  unsigned* bar = (unsigned*)(ws + WS_BAR);
  float* mc1 = ws + WS_MC1;
  float* mc2 = ws + WS_MC2;
  float* mc3 = ws + WS_MC3;
  float* mc4 = ws + WS_MC4;
  float* ml1 = ws + WS_ML1;
  float* ml2 = ws + WS_ML2;
  float* ml3 = ws + WS_ML3;
  float* xt  = ws + WS_XT;
  float* h1  = ws + WS_H1;
  float* h2  = ws + WS_H2;
  float* h3  = ws + WS_H3;
  float* h4  = ws + WS_H4;
  float* g1  = ws + WS_G1;
  float* g2  = ws + WS_G2;
  float* g3  = ws + WS_G3;

  __shared__ float tile[64 * 129];

  // ---- phase 0: mix weights, transpose x, zero out ----
  {
    int gid = blockIdx.x * BLOCK + threadIdx.x;
    const float* logits[7] = {P.c1w, P.c2w, P.c3w, P.c4w, P.l1w, P.l2w, P.l3w};
    float* outm[7] = {mc1, mc2, mc3, mc4, ml1, ml2, ml3};
    const int n[7] = {224, 896, 3584, 7168, 40960, 20480, 10240};
    int total = 224 + 896 + 3584 + 7168 + 40960 + 20480 + 10240;  // 83552
    if (gid < total) {
      int g = gid, seg = 0;
      while (seg < 6 && g >= n[seg]) { g -= n[seg]; ++seg; }
      mix_one(logits[seg] + (size_t)g * 16, outm[seg] + (size_t)g * 4);
    }
    if (blockIdx.x == GRID - 1 && threadIdx.x < 1280) P.out[threadIdx.x] = 0.f;
    if (blockIdx.x < 48) {
      int c    = blockIdx.x / 16;
      int pix0 = (blockIdx.x % 16) * 64;
      {
        int pix = threadIdx.x & 63;
        int b0  = threadIdx.x >> 6;  // 0..7
        #pragma unroll 4
        for (int i = 0; i < 16; ++i) {
          int b = b0 + i * 8;
          tile[pix * 129 + b] = P.x[((size_t)(b * 3 + c) * 1024) + pix0 + pix];
        }
      }
      __syncthreads();
      {
        int b  = threadIdx.x & 127;
        int p0 = threadIdx.x >> 7;  // 0..3
        #pragma unroll 4
        for (int i = 0; i < 16; ++i) {
          int pix = p0 + i * 4;
          xt[(size_t)(c * 1024 + pix0 + pix) * BATCH + b] = tile[pix * 129 + b];
        }
      }
    }
  }
  grid_barrier(bar, 0);

  conv_phase<9, 32, 32, 32, true, 4>(xt, P.c1i, mc1, h1);     // 8192 rows
  grid_barrier(bar, 1);
  conv_phase<32, 16, 16, 128, false, 4>(h1, P.c2i, mc2, h2);  // 8192 rows
  grid_barrier(bar, 2);
  conv_phase<128, 8, 8, 512, false, 4>(h2, P.c3i, mc3, h3);   // 8192 rows
  grid_barrier(bar, 3);
  conv_phase<512, 4, 4, 1024, false, 2>(h3, P.c4i, mc4, h4);  // 4096 rows
  grid_barrier(bar, 4);
  logic_phase<20>(h4, P.l1a, P.l1b, ml1, g1);                 // 40960 rows
  grid_barrier(bar, 5);
  logic_phase<10>(g1, P.l2a, P.l2b, ml2, g2);                 // 20480 rows
  grid_barrier(bar, 6);
  logic_phase<5>(g2, P.l3a, P.l3b, ml3, g3);                  // 10240 rows
  grid_barrier(bar, 7);
  gsum_phase(g3, P.out);
}

extern "C" void kernel_launch(void* const* d_in, const int* in_sizes, int n_in,
                              void* d_out, int out_size, void* d_ws, size_t ws_size,
                              hipStream_t stream) {
  Params P;
  P.x   = (const float*)d_in[0];
  P.c1i = (const int*)d_in[1];   P.c1w = (const float*)d_in[2];
  P.c2i = (const int*)d_in[3];   P.c2w = (const float*)d_in[4];
  P.c3i = (const int*)d_in[5];   P.c3w = (const float*)d_in[6];
  P.c4i = (const int*)d_in[7];   P.c4w = (const float*)d_in[8];
  P.l1a = (const int*)d_in[9];   P.l1b = (const int*)d_in[10];
  P.l1w = (const float*)d_in[11];
  P.l2a = (const int*)d_in[12];  P.l2b = (const int*)d_in[13];
  P.l2w = (const float*)d_in[14];
  P.l3a = (const int*)d_in[15];  P.l3b = (const int*)d_in[16];
  P.l3w = (const float*)d_in[17];
  P.ws  = (float*)d_ws;
  P.out = (float*)d_out;

  bar_init<<<1, 64, 0, stream>>>((unsigned*)d_ws);
  fused_net<<<GRID, BLOCK, 0, stream>>>(P);
}

// Round 6
// 200.778 us; speedup vs baseline: 3.6621x; 3.6621x over previous
//
#include <hip/hip_runtime.h>

#define BATCH 128

typedef float v2f __attribute__((ext_vector_type(2)));
typedef float v4f __attribute__((ext_vector_type(4)));

__device__ __constant__ float GC[16][4] = {
  {0,0,0,0},{0,0,0,1},{0,1,0,-1},{0,1,0,0},
  {0,0,1,-1},{0,0,1,0},{0,1,1,-2},{0,1,1,-1},
  {1,-1,-1,1},{1,-1,-1,2},{1,0,-1,0},{1,0,-1,1},
  {1,-1,0,0},{1,-1,0,1},{1,0,0,-1},{1,0,0,0}};

// ---- packed fp32 helpers (V_PK_FMA/MUL exist on gfx950; V_PK_MAX does NOT) ----
__device__ __forceinline__ v2f pk_mul(v2f a, v2f b) {
  v2f d;
  asm("v_pk_mul_f32 %0, %1, %2" : "=v"(d) : "v"(a), "v"(b));
  return d;
}
__device__ __forceinline__ v2f max2(v2f a, v2f b) {
  v2f d;
  d.x = fmaxf(a.x, b.x);
  d.y = fmaxf(a.y, b.y);
  return d;
}
// r = w0 + w1*a + w2*b + w3*(a*b), per half; w01=(w0,w1) pair, w23=(w2,w3).
__device__ __forceinline__ v2f gate2pk(v2f a, v2f b, v2f w01, v2f w23) {
  v2f t = pk_mul(a, b);
  v2f d;
  // d = a * w1 + w0
  asm("v_pk_fma_f32 %0, %1, %2, %2 op_sel:[0,1,0] op_sel_hi:[1,1,0]"
      : "=v"(d) : "v"(a), "v"(w01));
  // d = b * w2 + d
  asm("v_pk_fma_f32 %0, %1, %2, %0 op_sel:[0,0,0] op_sel_hi:[1,0,1]"
      : "+v"(d) : "v"(b), "v"(w23));
  // d = t * w3 + d
  asm("v_pk_fma_f32 %0, %1, %2, %0 op_sel:[0,1,0] op_sel_hi:[1,1,1]"
      : "+v"(d) : "v"(t), "v"(w23));
  return d;
}

__device__ __forceinline__ void mix_one(const float* lp, float* op) {
  // logits are 0.01*N(0,1) (+5 on slot 3): exp() safe without max-shift
  float e[16];
  float s = 0.f;
  #pragma unroll
  for (int i = 0; i < 16; ++i) { e[i] = __expf(lp[i]); s += e[i]; }
  float inv = 1.0f / s;
  float w0 = 0.f, w1 = 0.f, w2 = 0.f, w3 = 0.f;
  #pragma unroll
  for (int i = 0; i < 16; ++i) {
    float p = e[i] * inv;
    w0 = fmaf(p, GC[i][0], w0);
    w1 = fmaf(p, GC[i][1], w1);
    w2 = fmaf(p, GC[i][2], w2);
    w3 = fmaf(p, GC[i][3], w3);
  }
  op[0] = w0; op[1] = w1; op[2] = w2; op[3] = w3;
}

struct PrepArgs {
  const float* x;
  const float* logits[7];
  float* outm[7];
  float* xtb;
  float* out;
};

// blocks 0..326: weight mix; 327..470: transpose+binarize x; 471: zero out
__global__ __launch_bounds__(256) void prep_k(PrepArgs A) {
  __shared__ float tile[64 * 129];
  int blk = blockIdx.x;
  if (blk < 327) {
    int gid = blk * 256 + threadIdx.x;
    const int n[7] = {224, 896, 3584, 7168, 40960, 20480, 10240};
    if (gid < 83552) {
      int g = gid, seg = 0;
      while (seg < 6 && g >= n[seg]) { g -= n[seg]; ++seg; }
      mix_one(A.logits[seg] + (size_t)g * 16, A.outm[seg] + (size_t)g * 4);
    }
  } else if (blk < 327 + 144) {
    int tb = blk - 327;
    int c    = tb / 16;             // binarized channel 0..8
    int pix0 = (tb % 16) * 64;
    int ti = c / 3, rgb = c - ti * 3;
    float th = 0.25f * (float)(ti + 1);
    {
      int pix = threadIdx.x & 63;
      int b0  = threadIdx.x >> 6;
      #pragma unroll 4
      for (int i = 0; i < 32; ++i) {
        int b = b0 + i * 4;
        float xv = A.x[(size_t)(b * 3 + rgb) * 1024 + pix0 + pix];
        tile[pix * 129 + b] = (xv > th) ? 1.f : 0.f;
      }
    }
    __syncthreads();
    {
      int b  = threadIdx.x & 127;
      int p0 = threadIdx.x >> 7;
      #pragma unroll 4
      for (int i = 0; i < 32; ++i) {
        int pix = p0 + i * 2;
        A.xtb[(size_t)(c * 1024 + pix0 + pix) * BATCH + b] = tile[pix * 129 + b];
      }
    }
  } else {
    int t = threadIdx.x;
    #pragma unroll
    for (int i = 0; i < 5; ++i) A.out[t * 5 + i] = 0.f;  // 1280 floats
  }
}

// Transposed tree-conv+pool. One output row per wave (64 lanes x v2f = 128 batch).
// Row id is wave-uniform (readfirstlane) -> leaf/weight loads are s_load,
// boundary checks are uniform SALU branches.
template <int H, int W>
__global__ __launch_bounds__(256) void conv_t(
    const float* __restrict__ in_t, const int* __restrict__ li_g,
    const float* __restrict__ m, float* __restrict__ out_t) {
  constexpr int PH = H / 2, PWD = W / 2, PIX = PH * PWD;
  int wave = threadIdx.x >> 6;
  int b2   = threadIdx.x & 63;
  int q = __builtin_amdgcn_readfirstlane(blockIdx.x * 4 + wave);
  int o = q / PIX;
  int p = q - o * PIX;
  int ph = p / PWD;
  int pw = p - ph * PWD;

  const int* li = li_g + o * 8;
  const v4f* mv = (const v4f*)(m + o * 28);
  v4f g0 = mv[0], g1 = mv[1], g2 = mv[2], g3 = mv[3];
  v4f g4 = mv[4], g5 = mv[5], g6 = mv[6];

  v2f best = {-1e30f, -1e30f};
  #pragma unroll
  for (int half = 0; half < 2; ++half) {
    v2f v[2][8];
    #pragma unroll
    for (int l = 0; l < 8; ++l) {
      int idx = li[l];
      int c = idx / 9;
      int k = idx - c * 9;
      int di = k / 3 - 1;
      int dj = (k - (k / 3) * 3) - 1;
      const float* base = in_t + (size_t)(c * H * W) * BATCH;
      int y = 2 * ph + half + di;
      #pragma unroll
      for (int pi = 0; pi < 2; ++pi) {
        int x = 2 * pw + pi + dj;
        v2f val = {0.f, 0.f};
        if ((unsigned)y < (unsigned)H && (unsigned)x < (unsigned)W)
          val = ((const v2f*)(base + (size_t)(y * W + x) * BATCH))[b2];
        v[pi][l] = val;
      }
    }
    #pragma unroll
    for (int pi = 0; pi < 2; ++pi) {
      v2f u0 = gate2pk(v[pi][0], v[pi][1], g0.xy, g0.zw);
      v2f u1 = gate2pk(v[pi][2], v[pi][3], g1.xy, g1.zw);
      v2f u2 = gate2pk(v[pi][4], v[pi][5], g2.xy, g2.zw);
      v2f u3 = gate2pk(v[pi][6], v[pi][7], g3.xy, g3.zw);
      v2f s0 = gate2pk(u0, u1, g4.xy, g4.zw);
      v2f s1 = gate2pk(u2, u3, g5.xy, g5.zw);
      v2f r  = gate2pk(s0, s1, g6.xy, g6.zw);
      best = max2(best, r);
    }
  }
  ((v2f*)(out_t + (size_t)q * BATCH))[b2] = best;
}

// Logic layer, transposed (D,B). 16 rows per block (4/wave, stride-4).
__global__ __launch_bounds__(256) void logic_k(
    const float* __restrict__ in, const int* __restrict__ aidx,
    const int* __restrict__ bidx, const float* __restrict__ m,
    float* __restrict__ out) {
  int wave = threadIdx.x >> 6;
  int b2   = threadIdx.x & 63;
  int j0 = blockIdx.x * 16 + wave;
  #pragma unroll
  for (int it = 0; it < 4; ++it) {
    int j = __builtin_amdgcn_readfirstlane(j0 + it * 4);
    int ai = aidx[j];
    int bi = bidx[j];
    v4f w = ((const v4f*)m)[j];
    v2f a = ((const v2f*)(in + (size_t)ai * BATCH))[b2];
    v2f b = ((const v2f*)(in + (size_t)bi * BATCH))[b2];
    ((v2f*)(out + (size_t)j * BATCH))[b2] = gate2pk(a, b, w.xy, w.zw);
  }
}

// Final logic layer fused with group-sum: each wave owns 8 consecutive rows
// (8 | 1024 so a wave never straddles a class), accumulates per-lane partial
// sums, then 2 atomics per lane into out (zeroed by prep_k).
__global__ __launch_bounds__(256) void logic3_gsum_k(
    const float* __restrict__ in, const int* __restrict__ aidx,
    const int* __restrict__ bidx, const float* __restrict__ m,
    float* __restrict__ out) {
  int wave = threadIdx.x >> 6;
  int b2   = threadIdx.x & 63;
  int j0 = __builtin_amdgcn_readfirstlane((blockIdx.x * 4 + wave) * 8);
  int cls = j0 >> 10;
  v2f s = {0.f, 0.f};
  #pragma unroll
  for (int it = 0; it < 8; ++it) {
    int j = j0 + it;
    int ai = aidx[j];
    int bi = bidx[j];
    v4f w = ((const v4f*)m)[j];
    v2f a = ((const v2f*)(in + (size_t)ai * BATCH))[b2];
    v2f b = ((const v2f*)(in + (size_t)bi * BATCH))[b2];
    s += gate2pk(a, b, w.xy, w.zw);
  }
  atomicAdd(&out[(2 * b2) * 10 + cls], s.x * 0.01f);
  atomicAdd(&out[(2 * b2 + 1) * 10 + cls], s.y * 0.01f);
}

extern "C" void kernel_launch(void* const* d_in, const int* in_sizes, int n_in,
                              void* d_out, int out_size, void* d_ws, size_t ws_size,
                              hipStream_t stream) {
  const float* x   = (const float*)d_in[0];
  const int*   c1i = (const int*)d_in[1];
  const float* c1w = (const float*)d_in[2];
  const int*   c2i = (const int*)d_in[3];
  const float* c2w = (const float*)d_in[4];
  const int*   c3i = (const int*)d_in[5];
  const float* c3w = (const float*)d_in[6];
  const int*   c4i = (const int*)d_in[7];
  const float* c4w = (const float*)d_in[8];
  const int*   l1a = (const int*)d_in[9];
  const int*   l1b = (const int*)d_in[10];
  const float* l1w = (const float*)d_in[11];
  const int*   l2a = (const int*)d_in[12];
  const int*   l2b = (const int*)d_in[13];
  const float* l2w = (const float*)d_in[14];
  const int*   l3a = (const int*)d_in[15];
  const int*   l3b = (const int*)d_in[16];
  const float* l3w = (const float*)d_in[17];

  float* ws = (float*)d_ws;
  float* mc1 = ws;              // 224*4
  float* mc2 = mc1 + 896;       // 896*4
  float* mc3 = mc2 + 3584;      // 3584*4
  float* mc4 = mc3 + 14336;     // 7168*4
  float* ml1 = mc4 + 28672;     // 40960*4
  float* ml2 = ml1 + 163840;    // 20480*4
  float* ml3 = ml2 + 81920;     // 10240*4
  float* xtb = ml3 + 40960;     // 9216*128 binarized, transposed
  float* h1  = xtb + 1179648;   // 8192*128
  float* h2  = h1 + 1048576;    // 8192*128
  float* h3  = h2 + 1048576;    // 8192*128
  float* h4  = h3 + 1048576;    // 4096*128
  float* g1  = h4 + 524288;     // 40960*128
  float* g2  = g1 + 5242880;    // 20480*128

  PrepArgs A;
  A.x = x;
  A.logits[0] = c1w; A.outm[0] = mc1;
  A.logits[1] = c2w; A.outm[1] = mc2;
  A.logits[2] = c3w; A.outm[2] = mc3;
  A.logits[3] = c4w; A.outm[3] = mc4;
  A.logits[4] = l1w; A.outm[4] = ml1;
  A.logits[5] = l2w; A.outm[5] = ml2;
  A.logits[6] = l3w; A.outm[6] = ml3;
  A.xtb = xtb;
  A.out = (float*)d_out;
  prep_k<<<472, 256, 0, stream>>>(A);

  conv_t<32, 32><<<8192 / 4, 256, 0, stream>>>(xtb, c1i, mc1, h1);
  conv_t<16, 16><<<8192 / 4, 256, 0, stream>>>(h1, c2i, mc2, h2);
  conv_t<8, 8><<<8192 / 4, 256, 0, stream>>>(h2, c3i, mc3, h3);
  conv_t<4, 4><<<4096 / 4, 256, 0, stream>>>(h3, c4i, mc4, h4);

  logic_k<<<40960 / 16, 256, 0, stream>>>(h4, l1a, l1b, ml1, g1);
  logic_k<<<20480 / 16, 256, 0, stream>>>(g1, l2a, l2b, ml2, g2);
  logic3_gsum_k<<<10240 / 32, 256, 0, stream>>>(g2, l3a, l3b, ml3,
                                                (float*)d_out);
}

// Round 7
// 157.910 us; speedup vs baseline: 4.6563x; 1.2715x over previous
//
#include <hip/hip_runtime.h>

#define BATCH 128

typedef float v2f __attribute__((ext_vector_type(2)));
typedef float v4f __attribute__((ext_vector_type(4)));

__device__ __constant__ float GC[16][4] = {
  {0,0,0,0},{0,0,0,1},{0,1,0,-1},{0,1,0,0},
  {0,0,1,-1},{0,0,1,0},{0,1,1,-2},{0,1,1,-1},
  {1,-1,-1,1},{1,-1,-1,2},{1,0,-1,0},{1,0,-1,1},
  {1,-1,0,0},{1,-1,0,1},{1,0,0,-1},{1,0,0,0}};

// ---- packed fp32 helpers (V_PK_FMA/MUL exist on gfx950; V_PK_MAX does NOT) ----
__device__ __forceinline__ v2f pk_mul(v2f a, v2f b) {
  v2f d;
  asm("v_pk_mul_f32 %0, %1, %2" : "=v"(d) : "v"(a), "v"(b));
  return d;
}
__device__ __forceinline__ v2f max2(v2f a, v2f b) {
  v2f d;
  d.x = fmaxf(a.x, b.x);
  d.y = fmaxf(a.y, b.y);
  return d;
}
// r = w0 + w1*a + w2*b + w3*(a*b), per half; w01=(w0,w1) pair, w23=(w2,w3).
__device__ __forceinline__ v2f gate2pk(v2f a, v2f b, v2f w01, v2f w23) {
  v2f t = pk_mul(a, b);
  v2f d;
  // d = a * w1 + w0
  asm("v_pk_fma_f32 %0, %1, %2, %2 op_sel:[0,1,0] op_sel_hi:[1,1,0]"
      : "=v"(d) : "v"(a), "v"(w01));
  // d = b * w2 + d
  asm("v_pk_fma_f32 %0, %1, %2, %0 op_sel:[0,0,0] op_sel_hi:[1,0,1]"
      : "+v"(d) : "v"(b), "v"(w23));
  // d = t * w3 + d
  asm("v_pk_fma_f32 %0, %1, %2, %0 op_sel:[0,1,0] op_sel_hi:[1,1,1]"
      : "+v"(d) : "v"(t), "v"(w23));
  return d;
}

__device__ __forceinline__ void mix_one(const float* lp, float* op) {
  // logits are 0.01*N(0,1) (+5 on slot 3): exp() safe without max-shift
  float e[16];
  float s = 0.f;
  #pragma unroll
  for (int i = 0; i < 16; ++i) { e[i] = __expf(lp[i]); s += e[i]; }
  float inv = 1.0f / s;
  float w0 = 0.f, w1 = 0.f, w2 = 0.f, w3 = 0.f;
  #pragma unroll
  for (int i = 0; i < 16; ++i) {
    float p = e[i] * inv;
    w0 = fmaf(p, GC[i][0], w0);
    w1 = fmaf(p, GC[i][1], w1);
    w2 = fmaf(p, GC[i][2], w2);
    w3 = fmaf(p, GC[i][3], w3);
  }
  op[0] = w0; op[1] = w1; op[2] = w2; op[3] = w3;
}

struct PrepArgs {
  const float* x;
  const float* logits[7];
  float* outm[7];
  float* xtb;
  float* out;
};

// blocks 0..326: weight mix; 327..470: transpose+binarize x; 471: zero out
__global__ __launch_bounds__(256) void prep_k(PrepArgs A) {
  __shared__ float tile[64 * 129];
  int blk = blockIdx.x;
  if (blk < 327) {
    int gid = blk * 256 + threadIdx.x;
    const int n[7] = {224, 896, 3584, 7168, 40960, 20480, 10240};
    if (gid < 83552) {
      int g = gid, seg = 0;
      while (seg < 6 && g >= n[seg]) { g -= n[seg]; ++seg; }
      mix_one(A.logits[seg] + (size_t)g * 16, A.outm[seg] + (size_t)g * 4);
    }
  } else if (blk < 327 + 144) {
    int tb = blk - 327;
    int c    = tb / 16;             // binarized channel 0..8
    int pix0 = (tb % 16) * 64;
    int ti = c / 3, rgb = c - ti * 3;
    float th = 0.25f * (float)(ti + 1);
    {
      int pix = threadIdx.x & 63;
      int b0  = threadIdx.x >> 6;
      #pragma unroll 4
      for (int i = 0; i < 32; ++i) {
        int b = b0 + i * 4;
        float xv = A.x[(size_t)(b * 3 + rgb) * 1024 + pix0 + pix];
        tile[pix * 129 + b] = (xv > th) ? 1.f : 0.f;
      }
    }
    __syncthreads();
    {
      int b  = threadIdx.x & 127;
      int p0 = threadIdx.x >> 7;
      #pragma unroll 4
      for (int i = 0; i < 32; ++i) {
        int pix = p0 + i * 2;
        A.xtb[(size_t)(c * 1024 + pix0 + pix) * BATCH + b] = tile[pix * 129 + b];
      }
    }
  } else {
    int t = threadIdx.x;
    #pragma unroll
    for (int i = 0; i < 5; ++i) A.out[t * 5 + i] = 0.f;  // 1280 floats
  }
}

// Transposed tree-conv+pool. One output row per wave (64 lanes x v2f = 128 batch).
// Row id is wave-uniform (readfirstlane) -> leaf/weight loads are s_load,
// boundary checks are uniform SALU branches.
template <int H, int W>
__global__ __launch_bounds__(256) void conv_t(
    const float* __restrict__ in_t, const int* __restrict__ li_g,
    const float* __restrict__ m, float* __restrict__ out_t) {
  constexpr int PH = H / 2, PWD = W / 2, PIX = PH * PWD;
  int wave = threadIdx.x >> 6;
  int b2   = threadIdx.x & 63;
  int q = __builtin_amdgcn_readfirstlane(blockIdx.x * 4 + wave);
  int o = q / PIX;
  int p = q - o * PIX;
  int ph = p / PWD;
  int pw = p - ph * PWD;

  const int* li = li_g + o * 8;
  const v4f* mv = (const v4f*)(m + o * 28);
  v4f g0 = mv[0], g1 = mv[1], g2 = mv[2], g3 = mv[3];
  v4f g4 = mv[4], g5 = mv[5], g6 = mv[6];

  v2f best = {-1e30f, -1e30f};
  #pragma unroll
  for (int half = 0; half < 2; ++half) {
    v2f v[2][8];
    #pragma unroll
    for (int l = 0; l < 8; ++l) {
      int idx = li[l];
      int c = idx / 9;
      int k = idx - c * 9;
      int di = k / 3 - 1;
      int dj = (k - (k / 3) * 3) - 1;
      const float* base = in_t + (size_t)(c * H * W) * BATCH;
      int y = 2 * ph + half + di;
      #pragma unroll
      for (int pi = 0; pi < 2; ++pi) {
        int x = 2 * pw + pi + dj;
        v2f val = {0.f, 0.f};
        if ((unsigned)y < (unsigned)H && (unsigned)x < (unsigned)W)
          val = ((const v2f*)(base + (size_t)(y * W + x) * BATCH))[b2];
        v[pi][l] = val;
      }
    }
    #pragma unroll
    for (int pi = 0; pi < 2; ++pi) {
      v2f u0 = gate2pk(v[pi][0], v[pi][1], g0.xy, g0.zw);
      v2f u1 = gate2pk(v[pi][2], v[pi][3], g1.xy, g1.zw);
      v2f u2 = gate2pk(v[pi][4], v[pi][5], g2.xy, g2.zw);
      v2f u3 = gate2pk(v[pi][6], v[pi][7], g3.xy, g3.zw);
      v2f s0 = gate2pk(u0, u1, g4.xy, g4.zw);
      v2f s1 = gate2pk(u2, u3, g5.xy, g5.zw);
      v2f r  = gate2pk(s0, s1, g6.xy, g6.zw);
      best = max2(best, r);
    }
  }
  ((v2f*)(out_t + (size_t)q * BATCH))[b2] = best;
}

// Logic layer, transposed (D,B). 16 rows per block (4/wave, stride-4).
__global__ __launch_bounds__(256) void logic_k(
    const float* __restrict__ in, const int* __restrict__ aidx,
    const int* __restrict__ bidx, const float* __restrict__ m,
    float* __restrict__ out) {
  int wave = threadIdx.x >> 6;
  int b2   = threadIdx.x & 63;
  int j0 = blockIdx.x * 16 + wave;
  #pragma unroll
  for (int it = 0; it < 4; ++it) {
    int j = __builtin_amdgcn_readfirstlane(j0 + it * 4);
    int ai = aidx[j];
    int bi = bidx[j];
    v4f w = ((const v4f*)m)[j];
    v2f a = ((const v2f*)(in + (size_t)ai * BATCH))[b2];
    v2f b = ((const v2f*)(in + (size_t)bi * BATCH))[b2];
    ((v2f*)(out + (size_t)j * BATCH))[b2] = gate2pk(a, b, w.xy, w.zw);
  }
}

// Final logic layer fused with group-sum, reduction-hierarchy version:
// 40 blocks = 4 per class, 256 consecutive rows each (256 | 1024 so a block
// never straddles a class). Per-wave register accumulation over 64 rows ->
// LDS cross-wave reduce -> 128 atomics per block (5120 total, ~4 per cell).
__global__ __launch_bounds__(256) void logic3_gsum_k(
    const float* __restrict__ in, const int* __restrict__ aidx,
    const int* __restrict__ bidx, const float* __restrict__ m,
    float* __restrict__ out) {
  __shared__ v2f red[4][64];
  int wave = threadIdx.x >> 6;
  int b2   = threadIdx.x & 63;
  int base = __builtin_amdgcn_readfirstlane(blockIdx.x * 256 + wave * 64);
  int cls  = base >> 10;
  v2f s = {0.f, 0.f};
  #pragma unroll 4
  for (int it = 0; it < 64; ++it) {
    int j = base + it;
    int ai = aidx[j];
    int bi = bidx[j];
    v4f w = ((const v4f*)m)[j];
    v2f a = ((const v2f*)(in + (size_t)ai * BATCH))[b2];
    v2f b = ((const v2f*)(in + (size_t)bi * BATCH))[b2];
    s += gate2pk(a, b, w.xy, w.zw);
  }
  red[wave][b2] = s;
  __syncthreads();
  if (threadIdx.x < 64) {
    v2f t = red[0][b2] + red[1][b2] + red[2][b2] + red[3][b2];
    atomicAdd(&out[(2 * b2) * 10 + cls], t.x * 0.01f);
    atomicAdd(&out[(2 * b2 + 1) * 10 + cls], t.y * 0.01f);
  }
}

extern "C" void kernel_launch(void* const* d_in, const int* in_sizes, int n_in,
                              void* d_out, int out_size, void* d_ws, size_t ws_size,
                              hipStream_t stream) {
  const float* x   = (const float*)d_in[0];
  const int*   c1i = (const int*)d_in[1];
  const float* c1w = (const float*)d_in[2];
  const int*   c2i = (const int*)d_in[3];
  const float* c2w = (const float*)d_in[4];
  const int*   c3i = (const int*)d_in[5];
  const float* c3w = (const float*)d_in[6];
  const int*   c4i = (const int*)d_in[7];
  const float* c4w = (const float*)d_in[8];
  const int*   l1a = (const int*)d_in[9];
  const int*   l1b = (const int*)d_in[10];
  const float* l1w = (const float*)d_in[11];
  const int*   l2a = (const int*)d_in[12];
  const int*   l2b = (const int*)d_in[13];
  const float* l2w = (const float*)d_in[14];
  const int*   l3a = (const int*)d_in[15];
  const int*   l3b = (const int*)d_in[16];
  const float* l3w = (const float*)d_in[17];

  float* ws = (float*)d_ws;
  float* mc1 = ws;              // 224*4
  float* mc2 = mc1 + 896;       // 896*4
  float* mc3 = mc2 + 3584;      // 3584*4
  float* mc4 = mc3 + 14336;     // 7168*4
  float* ml1 = mc4 + 28672;     // 40960*4
  float* ml2 = ml1 + 163840;    // 20480*4
  float* ml3 = ml2 + 81920;     // 10240*4
  float* xtb = ml3 + 40960;     // 9216*128 binarized, transposed
  float* h1  = xtb + 1179648;   // 8192*128
  float* h2  = h1 + 1048576;    // 8192*128
  float* h3  = h2 + 1048576;    // 8192*128
  float* h4  = h3 + 1048576;    // 4096*128
  float* g1  = h4 + 524288;     // 40960*128
  float* g2  = g1 + 5242880;    // 20480*128

  PrepArgs A;
  A.x = x;
  A.logits[0] = c1w; A.outm[0] = mc1;
  A.logits[1] = c2w; A.outm[1] = mc2;
  A.logits[2] = c3w; A.outm[2] = mc3;
  A.logits[3] = c4w; A.outm[3] = mc4;
  A.logits[4] = l1w; A.outm[4] = ml1;
  A.logits[5] = l2w; A.outm[5] = ml2;
  A.logits[6] = l3w; A.outm[6] = ml3;
  A.xtb = xtb;
  A.out = (float*)d_out;
  prep_k<<<472, 256, 0, stream>>>(A);

  conv_t<32, 32><<<8192 / 4, 256, 0, stream>>>(xtb, c1i, mc1, h1);
  conv_t<16, 16><<<8192 / 4, 256, 0, stream>>>(h1, c2i, mc2, h2);
  conv_t<8, 8><<<8192 / 4, 256, 0, stream>>>(h2, c3i, mc3, h3);
  conv_t<4, 4><<<4096 / 4, 256, 0, stream>>>(h3, c4i, mc4, h4);

  logic_k<<<40960 / 16, 256, 0, stream>>>(h4, l1a, l1b, ml1, g1);
  logic_k<<<20480 / 16, 256, 0, stream>>>(g1, l2a, l2b, ml2, g2);
  logic3_gsum_k<<<40, 256, 0, stream>>>(g2, l3a, l3b, ml3, (float*)d_out);
}